// Round 8
// baseline (221.777 us; speedup 1.0000x reference)
//
#include <hip/hip_runtime.h>

typedef _Float16 f16;
typedef _Float16 f16x4 __attribute__((ext_vector_type(4)));
typedef _Float16 f16x8 __attribute__((ext_vector_type(8)));
typedef float f32x4 __attribute__((ext_vector_type(4)));
typedef float f32x16 __attribute__((ext_vector_type(16)));
typedef unsigned int u32;
typedef u32 u32x2 __attribute__((ext_vector_type(2)));
typedef u32 u32x4v __attribute__((ext_vector_type(4)));

#define MFMA_F16 __builtin_amdgcn_mfma_f32_32x32x16_f16

constexpr float LOG2E = 1.44269504088896f;
constexpr float THR   = 11.0f;     // defer-max threshold (log2 units)

__device__ __forceinline__ float fexp2(float x) { return __builtin_amdgcn_exp2f(x); }
__device__ __forceinline__ u32 pkrtz(float a, float b) {
    return __builtin_bit_cast(u32, __builtin_amdgcn_cvt_pkrtz(a, b));
}

// ===================== FAST PATH (uses d_ws >= 8 MB) ========================
// K global image : byte = (b*4096+key)*128 + ((ch*2) ^ ((key&7)<<4))   [4 MB]
// V^T global image: byte = KBYTES + (b*128+key/32)*4096 + ch*64
//                          + (((key&31)*2) ^ ((ch&7)<<3))              [4 MB]
constexpr size_t KBYTES  = (size_t)8 * 4096 * 128;
constexpr size_t WS_NEED = KBYTES * 2;

__global__ __launch_bounds__(256)
void precompute_kernel(const float* __restrict__ x, char* __restrict__ ws) {
    int t  = blockIdx.x * 256 + threadIdx.x;      // 131072 threads
    int c4 = (t & 15) * 4;                        // channel block
    int k4 = ((t >> 4) & 1023) * 4;               // key block
    int b  = t >> 14;                             // batch
    const float* src = x + ((size_t)b * 4096 + k4) * 64 + c4;
    f32x4 v[4];
    #pragma unroll
    for (int j = 0; j < 4; ++j) v[j] = *(const f32x4*)(src + j * 64);
    char* Kg = ws;
    char* Vg = ws + KBYTES;
    #pragma unroll
    for (int j = 0; j < 4; ++j) {
        int key = k4 + j;
        u32x2 kp = { pkrtz(v[j][0], v[j][1]), pkrtz(v[j][2], v[j][3]) };
        *(u32x2*)(Kg + ((size_t)(b * 4096 + key)) * 128 + ((c4 * 2) ^ ((key & 7) << 4))) = kp;
    }
    int tile = k4 >> 5, kl = k4 & 31;
    #pragma unroll
    for (int i = 0; i < 4; ++i) {
        int ch = c4 + i;
        u32x2 vp = { pkrtz(v[0][i], v[1][i]), pkrtz(v[2][i], v[3][i]) };
        *(u32x2*)(Vg + ((size_t)(b * 128 + tile)) * 4096 + ch * 64 + ((kl * 2) ^ ((ch & 7) << 3))) = vp;
    }
}

constexpr int NTI  = 32;        // 4096 keys / 4 groups / 32 per tile
constexpr int GLDS = 16384;     // per group: 2 bufs x (K 4096 + V 4096)
constexpr int MG_PM = 52224, MG_PL = 52992, MG_EP = 53760;  // smem = 70656

__device__ __forceinline__ void gload16(const void* g, void* l) {
    __builtin_amdgcn_global_load_lds(
        (const __attribute__((address_space(1))) void*)g,
        (__attribute__((address_space(3))) void*)l, 16, 0, 0);
}

__global__ __launch_bounds__(512, 4)
void attn_fast(const char* __restrict__ ws, const float* __restrict__ x,
               const float* __restrict__ gamma, float* __restrict__ out) {
    __shared__ __align__(16) unsigned char smem[70656];
    const char* Kg = ws;
    const char* Vg = ws + KBYTES;

    const int tid = threadIdx.x;
    const int w   = tid >> 6;
    const int g   = w >> 1;            // kv group 0..3
    const int qw  = w & 1;             // q sub-tile 0..1
    const int l   = tid & 63;
    const int h   = l >> 5;
    const int q   = l & 31;
    const int bid = blockIdx.x;
    const int b   = bid & 7;           // XCD-affine
    const int qt  = bid >> 3;          // 0..63
    const float* xb = x + (size_t)b * (4096 * 64);
    const int qbase = qt * 64;
    const int qg   = qw * 32 + q;
    const int qrow = qbase + qg;

    // ---- Q fragments from x, pre-scaled by log2(e) ----
    f16x8 Qf[4];
    {
        const float* qs = xb + (size_t)qrow * 64 + h * 8;
        #pragma unroll
        for (int kk = 0; kk < 4; ++kk) {
            f32x4 a  = *(const f32x4*)(qs + kk * 16);
            f32x4 c2 = *(const f32x4*)(qs + kk * 16 + 4);
            f16x8 f;
            f[0] = (f16)(a[0] * LOG2E);  f[1] = (f16)(a[1] * LOG2E);
            f[2] = (f16)(a[2] * LOG2E);  f[3] = (f16)(a[3] * LOG2E);
            f[4] = (f16)(c2[0] * LOG2E); f[5] = (f16)(c2[1] * LOG2E);
            f[6] = (f16)(c2[2] * LOG2E); f[7] = (f16)(c2[3] * LOG2E);
            Qf[kk] = f;
        }
    }

    // ---- staging: pure global_load_lds from pre-swizzled global ----
    const char* gK = Kg + ((size_t)(b * 4096 + g * 1024)) * 128 + l * 16;
    const char* gV = Vg + ((size_t)(b * 128  + g * 32 )) * 4096 + l * 16;
    const char* gsrc = qw ? gV : gK;
    char* sdst = (char*)smem + g * GLDS + (qw ? 4096 : 0);

    auto stage = [&](int kt, int sel) {
        const char* s = gsrc + (size_t)kt * 4096;
        char* d = sdst + sel * 8192;
        gload16(s,        d);
        gload16(s + 1024, d + 1024);
        gload16(s + 2048, d + 2048);
        gload16(s + 3072, d + 3072);
    };

    // ---- loop-invariant fragment pointers (sel via imm offset) ----
    const char* kbase = (const char*)smem + g * GLDS;      // K buf, sel=0
    const char* vbase = kbase + 4096;                      // V buf, sel=0
    const int xk = (q & 7) << 4;
    const int xv = (q & 7) << 3;
    const char* kp[4];
    #pragma unroll
    for (int kk = 0; kk < 4; ++kk)
        kp[kk] = kbase + q * 128 + ((kk * 32 + h * 16) ^ xk);
    const char* vplo[2]; const char* vphi[2];
    #pragma unroll
    for (int kk = 0; kk < 2; ++kk) {
        int c = kk * 32 + h * 16;
        vplo[kk] = vbase + q * 64 + (c ^ xv);
        vphi[kk] = vbase + q * 64 + ((c + 8) ^ xv);
    }

    f16x8 ones8;
    #pragma unroll
    for (int j = 0; j < 8; ++j) ones8[j] = (f16)1.0f;

    f32x16 ot[2] = {};
    f32x16 accl  = {};
    float m_run = -INFINITY;

    stage(0, 0);
    __syncthreads();

    #pragma unroll 2
    for (int kt = 0; kt < NTI; ++kt) {
        const int sel = kt & 1;
        const int so  = sel * 8192;                 // folds to imm under unroll
        if (kt + 1 < NTI) stage(kt + 1, sel ^ 1);   // prefetch next tile

        // ---- S'^T = K · (log2e·Q)^T ----
        f32x16 st = {};
        __builtin_amdgcn_s_setprio(1);
        #pragma unroll
        for (int kk = 0; kk < 4; ++kk) {
            f16x8 kf = *(const f16x8*)(kp[kk] + so);   // single ds_read_b128
            st = MFMA_F16(kf, Qf[kk], st, 0, 0, 0);
        }
        __builtin_amdgcn_s_setprio(0);

        // ---- online softmax (log2 domain) ----
        float t0 = fmaxf(fmaxf(st[0], st[1]), st[2]);
        float t1 = fmaxf(fmaxf(st[3], st[4]), st[5]);
        float t2 = fmaxf(fmaxf(st[6], st[7]), st[8]);
        float t3 = fmaxf(fmaxf(st[9], st[10]), st[11]);
        float t4 = fmaxf(fmaxf(st[12], st[13]), st[14]);
        float pmax = fmaxf(fmaxf(fmaxf(t0, t1), fmaxf(t2, t3)), fmaxf(t4, st[15]));
        pmax = fmaxf(pmax, __shfl_xor(pmax, 32, 64));   // proven cross-half max

        if (!__all(pmax - m_run <= THR)) {          // defer-max (T13)
            float m_new = fmaxf(m_run, pmax);
            float scf = fexp2(m_run - m_new);
            #pragma unroll
            for (int r = 0; r < 16; ++r) {
                ot[0][r] *= scf; ot[1][r] *= scf; accl[r] *= scf;
            }
            m_run = m_new;
        }

        #pragma unroll
        for (int r = 0; r < 16; ++r) st[r] = fexp2(st[r] - m_run);

        // ---- P -> f16 B-fragments (pkrtz + proven shfl_xor exchange) ----
        // st[r] holds key = (r&3) + 8*(r>>2) + 4h; frag kk needs keys 16kk+8h+j
        f16x8 Pf[2];
        #pragma unroll
        for (int kk = 0; kk < 2; ++kk) {
            int sa = 2 * kk + h;                 // s-slot I need
            int sb = 2 * kk + (1 - h);           // s-slot my partner needs
            u32 ua0 = pkrtz(st[sa*4+0], st[sa*4+1]);
            u32 ua1 = pkrtz(st[sa*4+2], st[sa*4+3]);
            u32 ub0 = pkrtz(st[sb*4+0], st[sb*4+1]);
            u32 ub1 = pkrtz(st[sb*4+2], st[sb*4+3]);
            u32 r0 = __shfl_xor(ub0, 32, 64);
            u32 r1 = __shfl_xor(ub1, 32, 64);
            u32x4v uv;
            uv[0] = h ? r0 : ua0;                // j=0..3 from h_src=0
            uv[1] = h ? r1 : ua1;
            uv[2] = h ? ua0 : r0;                // j=4..7 from h_src=1
            uv[3] = h ? ua1 : r1;
            Pf[kk] = __builtin_bit_cast(f16x8, uv);
        }

        // ---- row-sum on the matrix pipe: accl += ones · P ----
        accl = MFMA_F16(ones8, Pf[0], accl, 0, 0, 0);
        accl = MFMA_F16(ones8, Pf[1], accl, 0, 0, 0);

        // ---- O^T += V^T · P^T ----
        __builtin_amdgcn_s_setprio(1);
        #pragma unroll
        for (int mI = 0; mI < 2; ++mI) {
            #pragma unroll
            for (int kk = 0; kk < 2; ++kk) {
                f16x4 lo = *(const f16x4*)(vplo[kk] + so + mI * 2048);
                f16x4 hi = *(const f16x4*)(vphi[kk] + so + mI * 2048);
                f16x8 vf = __builtin_shufflevector(lo, hi, 0, 1, 2, 3, 4, 5, 6, 7);
                ot[mI] = MFMA_F16(vf, Pf[kk], ot[mI], 0, 0, 0);
            }
        }
        __builtin_amdgcn_s_setprio(0);

        __syncthreads();
    }

    // ---- intra-block flash-decoding merge of the 4 kv-group partials ----
    float l_run = accl[0];
    float* pO = (float*)smem;                    // [3][64][68]
    float* pm = (float*)(smem + MG_PM);          // [3][64]
    float* pl = (float*)(smem + MG_PL);          // [3][64]

    if (g > 0) {
        float* po = pO + (size_t)(g - 1) * (64 * 68) + qg * 68;
        #pragma unroll
        for (int mI = 0; mI < 2; ++mI)
            #pragma unroll
            for (int j = 0; j < 4; ++j) {
                f32x4 v = { ot[mI][4*j], ot[mI][4*j+1], ot[mI][4*j+2], ot[mI][4*j+3] };
                *(f32x4*)(po + mI * 32 + j * 8 + h * 4) = v;
            }
        if (h == 0) { pm[(g - 1) * 64 + qg] = m_run; pl[(g - 1) * 64 + qg] = l_run; }
    }
    __syncthreads();

    if (g == 0) {
        float m1 = pm[qg], m2 = pm[64 + qg], m3 = pm[128 + qg];
        float l1 = pl[qg], l2 = pl[64 + qg], l3 = pl[128 + qg];
        float M  = fmaxf(fmaxf(m_run, m1), fmaxf(m2, m3));
        float a0 = fexp2(m_run - M);
        float ag[3] = { fexp2(m1 - M), fexp2(m2 - M), fexp2(m3 - M) };
        float L = l_run * a0 + l1 * ag[0] + l2 * ag[1] + l3 * ag[2];
        #pragma unroll
        for (int mI = 0; mI < 2; ++mI)
            #pragma unroll
            for (int r = 0; r < 16; ++r) ot[mI][r] *= a0;
        #pragma unroll
        for (int gg = 0; gg < 3; ++gg) {
            const float* po = pO + (size_t)gg * (64 * 68) + qg * 68;
            #pragma unroll
            for (int mI = 0; mI < 2; ++mI)
                #pragma unroll
                for (int j = 0; j < 4; ++j) {
                    f32x4 v = *(const f32x4*)(po + mI * 32 + j * 8 + h * 4);
                    ot[mI][4*j+0] += ag[gg] * v[0];
                    ot[mI][4*j+1] += ag[gg] * v[1];
                    ot[mI][4*j+2] += ag[gg] * v[2];
                    ot[mI][4*j+3] += ag[gg] * v[3];
                }
        }

        float invl = 1.0f / L;
        float* ep = (float*)(smem + MG_EP + qw * 8448);   // [64][33] per q-wave
        #pragma unroll
        for (int mI = 0; mI < 2; ++mI)
            #pragma unroll
            for (int r = 0; r < 16; ++r) {
                int c = 32 * mI + (r & 3) + 8 * (r >> 2) + 4 * h;
                ep[c * 33 + q] = ot[mI][r] * invl;
            }

        const float gm = gamma[0];
        float* ob = out + (size_t)b * (4096 * 64);
        #pragma unroll
        for (int it = 0; it < 8; ++it) {
            int ql  = it * 4 + (l >> 4);
            int cc0 = (l & 15) * 4;
            f32x4 o;
            o[0] = ep[(cc0 + 0) * 33 + ql];
            o[1] = ep[(cc0 + 1) * 33 + ql];
            o[2] = ep[(cc0 + 2) * 33 + ql];
            o[3] = ep[(cc0 + 3) * 33 + ql];
            int row = qbase + qw * 32 + ql;
            f32x4 xi = *(const f32x4*)(xb + (size_t)row * 64 + cc0);
            f32x4 res = { gm * o[0] + xi[0], gm * o[1] + xi[1],
                          gm * o[2] + xi[2], gm * o[3] + xi[3] };
            *(f32x4*)(ob + (size_t)row * 64 + cc0) = res;
        }
    }
}

// ============ REPAIR / FALLBACK (round-4 kernel + finite-scan gate) =========
namespace fb {

constexpr int KV = 32, NT = 32, KEYS_PER_GRP = 1024;
constexpr int KROW = 136, VROW = 72, VOFF = 32 * KROW, BUFSZ = VOFF + 64 * VROW;
constexpr int GSTRIDE = 2 * BUFSZ;
constexpr int PM_OFF = 52224, PL_OFF = PM_OFF + 768, EP_OFF = 53760;

__device__ __forceinline__ f16x8 ld8(const char* p) {
    f16x4 lo = *(const f16x4*)p;
    f16x4 hi = *(const f16x4*)(p + 8);
    return __builtin_shufflevector(lo, hi, 0, 1, 2, 3, 4, 5, 6, 7);
}

__global__ __launch_bounds__(512, 4)
void channel_attn_fb(const float* __restrict__ x, const float* __restrict__ gamma,
                     float* __restrict__ out, int force) {
    __shared__ __align__(16) unsigned char smem[71680];
    const int tid = threadIdx.x;
    const int w = tid >> 6, g = w >> 1, qw = w & 1;
    const int l = tid & 63, h = l >> 5, q = l & 31;
    const int bid = blockIdx.x, b = bid & 7, qt = bid >> 3;
    const float* xb = x + (size_t)b * (4096 * 64);
    const int qbase = qt * 64, qg = qw * 32 + q, qrow = qbase + qg;

    // ---- gate: recompute only if our 64x64 out tile has non-finite values ----
    {
        int bad = force;
        const float* ob0 = out + (size_t)b * (4096 * 64) + (size_t)qbase * 64;
        const f32x4* p4 = (const f32x4*)ob0 + (size_t)tid * 2;   // 512 thr x 8 f32
        f32x4 v0 = p4[0], v1 = p4[1];
        #pragma unroll
        for (int i = 0; i < 4; ++i) {
            if (!(__builtin_fabsf(v0[i]) <= 1e30f)) bad = 1;   // catches NaN & inf
            if (!(__builtin_fabsf(v1[i]) <= 1e30f)) bad = 1;
        }
        if (!__syncthreads_or(bad)) return;
    }

    f16x8 Qf[4];
    {
        const float* qs = xb + (size_t)qrow * 64 + h * 8;
        #pragma unroll
        for (int kk = 0; kk < 4; ++kk) {
            f32x4 a = *(const f32x4*)(qs + kk * 16);
            f32x4 c2 = *(const f32x4*)(qs + kk * 16 + 4);
            f16x8 f;
            f[0]=(f16)(a[0]*LOG2E); f[1]=(f16)(a[1]*LOG2E); f[2]=(f16)(a[2]*LOG2E); f[3]=(f16)(a[3]*LOG2E);
            f[4]=(f16)(c2[0]*LOG2E);f[5]=(f16)(c2[1]*LOG2E);f[6]=(f16)(c2[2]*LOG2E);f[7]=(f16)(c2[3]*LOG2E);
            Qf[kk] = f;
        }
    }
    const int c0 = (l & 15) * 4, kr0 = qw * 16 + (l >> 4) * 4;
    f32x4 stg[4];
    char* gb = (char*)smem + g * GSTRIDE;
    const float* kvsrc = xb + ((size_t)(g * KEYS_PER_GRP + kr0) * 64 + c0);
    auto stage_load = [&]() {
        #pragma unroll
        for (int j = 0; j < 4; ++j) stg[j] = *(const f32x4*)(kvsrc + j * 64);
        kvsrc += KV * 64;
    };
    auto stage_write = [&](int sel) {
        char* kb = gb + sel * BUFSZ;
        char* vb = kb + VOFF;
        #pragma unroll
        for (int j = 0; j < 4; ++j) {
            u32x2 kv2 = { pkrtz(stg[j][0], stg[j][1]), pkrtz(stg[j][2], stg[j][3]) };
            *(u32x2*)(kb + (kr0 + j) * KROW + c0 * 2) = kv2;
        }
        #pragma unroll
        for (int i = 0; i < 4; ++i) {
            u32x2 vv = { pkrtz(stg[0][i], stg[1][i]), pkrtz(stg[2][i], stg[3][i]) };
            *(u32x2*)(vb + (c0 + i) * VROW + kr0 * 2) = vv;
        }
    };
    f32x16 ot[2] = {};
    float m_run = -INFINITY, l_run = 0.f;
    stage_load(); stage_write(0); __syncthreads();
    #pragma unroll 2
    for (int kt = 0; kt < NT; ++kt) {
        const int sel = kt & 1;
        const char* kb = gb + sel * BUFSZ;
        const char* vb = kb + VOFF;
        if (kt + 1 < NT) stage_load();
        f32x16 st = {};
        __builtin_amdgcn_s_setprio(1);
        #pragma unroll
        for (int kk = 0; kk < 4; ++kk)
            st = MFMA_F16(ld8(kb + q * KROW + h * 16 + kk * 32), Qf[kk], st, 0, 0, 0);
        __builtin_amdgcn_s_setprio(0);
        float m01=fmaxf(st[0],st[1]), m23=fmaxf(st[2],st[3]), m45=fmaxf(st[4],st[5]), m67=fmaxf(st[6],st[7]);
        float m89=fmaxf(st[8],st[9]), mab=fmaxf(st[10],st[11]), mcd=fmaxf(st[12],st[13]), mef=fmaxf(st[14],st[15]);
        float pmax = fmaxf(fmaxf(fmaxf(m01,m23),fmaxf(m45,m67)), fmaxf(fmaxf(m89,mab),fmaxf(mcd,mef)));
        pmax = fmaxf(pmax, __shfl_xor(pmax, 32, 64));
        if (!__all(pmax - m_run <= THR)) {
            float m_new = fmaxf(m_run, pmax);
            float scf = fexp2(m_run - m_new);
            l_run *= scf;
            #pragma unroll
            for (int mI = 0; mI < 2; ++mI)
                #pragma unroll
                for (int r = 0; r < 16; ++r) ot[mI][r] *= scf;
            m_run = m_new;
        }
        float rs4[4] = {0.f,0.f,0.f,0.f};
        #pragma unroll
        for (int r = 0; r < 16; ++r) { float p = fexp2(st[r] - m_run); st[r] = p; rs4[r & 3] += p; }
        float rs = (rs4[0]+rs4[1]) + (rs4[2]+rs4[3]);
        rs += __shfl_xor(rs, 32, 64);
        l_run += rs;
        f16x8 Pf[2];
        #pragma unroll
        for (int kk = 0; kk < 2; ++kk) {
            int sa = 2*kk + h, sb = 2*kk + (1-h);
            u32 ua0 = pkrtz(st[sa*4+0], st[sa*4+1]);
            u32 ua1 = pkrtz(st[sa*4+2], st[sa*4+3]);
            u32 ub0 = pkrtz(st[sb*4+0], st[sb*4+1]);
            u32 ub1 = pkrtz(st[sb*4+2], st[sb*4+3]);
            u32 r0 = __shfl_xor(ub0, 32, 64);
            u32 r1 = __shfl_xor(ub1, 32, 64);
            u32x4v uv;
            uv[0] = h ? r0 : ua0; uv[1] = h ? r1 : ua1;
            uv[2] = h ? ua0 : r0; uv[3] = h ? ua1 : r1;
            Pf[kk] = __builtin_bit_cast(f16x8, uv);
        }
        if (kt + 1 < NT) stage_write(sel ^ 1);
        __builtin_amdgcn_s_setprio(1);
        #pragma unroll
        for (int mI = 0; mI < 2; ++mI) {
            f32x16 acc = ot[mI];
            #pragma unroll
            for (int kk = 0; kk < 2; ++kk)
                acc = MFMA_F16(ld8(vb + (q + 32*mI) * VROW + h * 16 + kk * 32), Pf[kk], acc, 0, 0, 0);
            ot[mI] = acc;
        }
        __builtin_amdgcn_s_setprio(0);
        __syncthreads();
    }
    float* pO = (float*)smem;
    float* pm = (float*)(smem + PM_OFF);
    float* pl = (float*)(smem + PL_OFF);
    if (g > 0) {
        float* po = pO + (size_t)(g - 1) * (64 * 68) + qg * 68;
        #pragma unroll
        for (int mI = 0; mI < 2; ++mI)
            #pragma unroll
            for (int j = 0; j < 4; ++j) {
                f32x4 v = { ot[mI][4*j], ot[mI][4*j+1], ot[mI][4*j+2], ot[mI][4*j+3] };
                *(f32x4*)(po + mI * 32 + j * 8 + h * 4) = v;
            }
        if (h == 0) { pm[(g-1)*64 + qg] = m_run; pl[(g-1)*64 + qg] = l_run; }
    }
    __syncthreads();
    if (g == 0) {
        float m1 = pm[qg], m2 = pm[64+qg], m3 = pm[128+qg];
        float l1 = pl[qg], l2 = pl[64+qg], l3 = pl[128+qg];
        float M = fmaxf(fmaxf(m_run, m1), fmaxf(m2, m3));
        float a0 = fexp2(m_run - M);
        float ag[3] = { fexp2(m1 - M), fexp2(m2 - M), fexp2(m3 - M) };
        float L = l_run * a0 + l1*ag[0] + l2*ag[1] + l3*ag[2];
        #pragma unroll
        for (int mI = 0; mI < 2; ++mI)
            #pragma unroll
            for (int r = 0; r < 16; ++r) ot[mI][r] *= a0;
        #pragma unroll
        for (int gg = 0; gg < 3; ++gg) {
            const float* po = pO + (size_t)gg * (64 * 68) + qg * 68;
            #pragma unroll
            for (int mI = 0; mI < 2; ++mI)
                #pragma unroll
                for (int j = 0; j < 4; ++j) {
                    f32x4 v = *(const f32x4*)(po + mI * 32 + j * 8 + h * 4);
                    ot[mI][4*j+0] += ag[gg]*v[0]; ot[mI][4*j+1] += ag[gg]*v[1];
                    ot[mI][4*j+2] += ag[gg]*v[2]; ot[mI][4*j+3] += ag[gg]*v[3];
                }
        }
        float invl = 1.0f / L;
        float* ep = (float*)(smem + EP_OFF + qw * 8448);
        #pragma unroll
        for (int mI = 0; mI < 2; ++mI)
            #pragma unroll
            for (int r = 0; r < 16; ++r) {
                int c = 32*mI + (r & 3) + 8*(r >> 2) + 4*h;
                ep[c * 33 + q] = ot[mI][r] * invl;
            }
        const float gm = gamma[0];
        float* ob = out + (size_t)b * (4096 * 64);
        #pragma unroll
        for (int it = 0; it < 8; ++it) {
            int ql = it * 4 + (l >> 4);
            int cc0 = (l & 15) * 4;
            f32x4 o;
            o[0] = ep[(cc0+0)*33+ql]; o[1] = ep[(cc0+1)*33+ql];
            o[2] = ep[(cc0+2)*33+ql]; o[3] = ep[(cc0+3)*33+ql];
            int row = qbase + qw * 32 + ql;
            f32x4 xi = *(const f32x4*)(xb + (size_t)row * 64 + cc0);
            f32x4 res = { gm*o[0]+xi[0], gm*o[1]+xi[1], gm*o[2]+xi[2], gm*o[3]+xi[3] };
            *(f32x4*)(ob + (size_t)row * 64 + cc0) = res;
        }
    }
}

}  // namespace fb

extern "C" void kernel_launch(void* const* d_in, const int* in_sizes, int n_in,
                              void* d_out, int out_size, void* d_ws, size_t ws_size,
                              hipStream_t stream) {
    const float* x     = (const float*)d_in[0];
    const float* gamma = (const float*)d_in[1];
    float* out         = (float*)d_out;
    if (ws_size >= WS_NEED && d_ws != nullptr) {
        precompute_kernel<<<dim3(512), dim3(256), 0, stream>>>(x, (char*)d_ws);
        attn_fast<<<dim3(512), dim3(512), 0, stream>>>((const char*)d_ws, x, gamma, out);
        fb::channel_attn_fb<<<dim3(512), dim3(512), 0, stream>>>(x, gamma, out, 0);
    } else {
        fb::channel_attn_fb<<<dim3(512), dim3(512), 0, stream>>>(x, gamma, out, 1);
    }
}